// Round 1
// baseline (1382.986 us; speedup 1.0000x reference)
//
#include <hip/hip_runtime.h>
#include <math.h>

#define BATCH  32
#define FEATC  512
#define SDIM   128
#define NPIX   (SDIM*SDIM)      // 16384
#define CDIM   8
#define KSTEPS 7
#define SLAB   (BATCH*NPIX)     // 524288 floats per (B,1,S,S) slab

// argmax combine: strict greater wins; on exact tie, smaller index wins
// (matches jnp.argmax first-occurrence semantics)
__device__ __forceinline__ void amax_comb(float& v, int& i, float v2, int i2) {
    if (v2 > v || (v2 == v && i2 < i)) { v = v2; i = i2; }
}

__device__ __forceinline__ void wave_argmax(float& v, int& i) {
#pragma unroll
    for (int off = 32; off > 0; off >>= 1) {
        float v2 = __shfl_down(v, off);
        int   i2 = __shfl_down(i, off);
        amax_comb(v, i, v2, i2);
    }
}

// -------- conv: colour = gate*(W@F + b) + uv ; delta = x[:, 6:8] --------
// grid 512 = 32 batches x 16 tiles, block 256, 4 pixels/thread (float4)
__global__ __launch_bounds__(256) void conv_kernel(
    const float* __restrict__ feat, const float* __restrict__ randp,
    const float* __restrict__ conv_w, const float* __restrict__ conv_b,
    const float* __restrict__ gate, const float* __restrict__ uv,
    float* __restrict__ colour, float* __restrict__ delta,
    float* __restrict__ ws_val, int* __restrict__ ws_idx)
{
    __shared__ float wT[FEATC*CDIM];   // wT[c*8+o] : 16 KB
    __shared__ float sv[4]; __shared__ int si[4];
    const int tid = threadIdx.x;
    for (int i = tid; i < FEATC*CDIM; i += 256) {
        int o = i >> 9, c = i & 511;   // conv_w is (CD, FEAT): i = o*512 + c
        wT[c*CDIM + o] = conv_w[i];
    }
    __syncthreads();

    const int b   = blockIdx.x >> 4;
    const int pix = (blockIdx.x & 15) * 1024 + tid * 4;
    const float* fb = feat + (size_t)b * FEATC * NPIX + pix;

    float acc[CDIM][4];
#pragma unroll
    for (int o = 0; o < CDIM; o++) { acc[o][0]=0.f; acc[o][1]=0.f; acc[o][2]=0.f; acc[o][3]=0.f; }

#pragma unroll 4
    for (int c = 0; c < FEATC; c++) {
        const float4 f  = *(const float4*)(fb + (size_t)c * NPIX);
        const float4 wa = *(const float4*)(wT + c * CDIM);
        const float4 wb = *(const float4*)(wT + c * CDIM + 4);
        float wv[8];
        *(float4*)wv = wa; *(float4*)(wv + 4) = wb;
#pragma unroll
        for (int o = 0; o < CDIM; o++) {
            const float w = wv[o];
            acc[o][0] += f.x * w; acc[o][1] += f.y * w;
            acc[o][2] += f.z * w; acc[o][3] += f.w * w;
        }
    }

    const float g = gate[0];
#pragma unroll
    for (int o = 0; o < CDIM; o++) {
        const float bo = conv_b[o];
        float4 x;
        x.x = g * (acc[o][0] + bo); x.y = g * (acc[o][1] + bo);
        x.z = g * (acc[o][2] + bo); x.w = g * (acc[o][3] + bo);
        const float4 u = *(const float4*)(uv + o * NPIX + pix);
        float4 col = { x.x + u.x, x.y + u.y, x.z + u.z, x.w + u.w };
        *(float4*)(colour + (b * CDIM + o) * NPIX + pix) = col;
        if (o >= CDIM - 2)
            *(float4*)(delta + (b * 2 + (o - (CDIM - 2))) * NPIX + pix) = x;
    }

    // step-0 argmax partials: pp_0 = rand_pixel * exp(0) = rand_pixel (exact)
    const float4 r = *(const float4*)(randp + b * NPIX + pix);
    float v = r.x; int idx = pix;
    amax_comb(v, idx, r.y, pix + 1);
    amax_comb(v, idx, r.z, pix + 2);
    amax_comb(v, idx, r.w, pix + 3);
    wave_argmax(v, idx);
    if ((tid & 63) == 0) { sv[tid >> 6] = v; si[tid >> 6] = idx; }
    __syncthreads();
    if (tid == 0) {
#pragma unroll
        for (int w = 1; w < 4; w++) amax_comb(v, idx, sv[w], si[w]);
        ws_val[blockIdx.x] = v; ws_idx[blockIdx.x] = idx;
    }
}

// -------- reduce 16 per-batch partials -> idx, gather seed --------
// grid 32 (one block per batch), block 64 (one wave)
__global__ __launch_bounds__(64) void reduce_seed_kernel(
    const float* __restrict__ ws_val, const int* __restrict__ ws_idx,
    const float* __restrict__ colour, float* __restrict__ seed_ws,
    float* __restrict__ seeds_out, int k)
{
    const int b = blockIdx.x, t = threadIdx.x;
    float v = -INFINITY; int idx = 0x7fffffff;
    if (t < 16) { v = ws_val[b * 16 + t]; idx = ws_idx[b * 16 + t]; }
    wave_argmax(v, idx);
    idx = __shfl(idx, 0);
    if (t < CDIM) {
        const float s = colour[(b * CDIM + t) * NPIX + idx];
        seed_ws[b * CDIM + t] = s;
        seeds_out[(k * BATCH + b) * CDIM + t] = s;
    }
}

// -------- scan step k: alpha, log_m, new log_s, next-step argmax partials ----
// grid 512 = 32 batches x 16 tiles, block 256, 4 pixels/thread
__global__ __launch_bounds__(256) void step_kernel(
    const float* __restrict__ colour, const float* __restrict__ randp,
    const float* __restrict__ log_sigma, const float* __restrict__ seed_ws,
    float* __restrict__ LM, float* __restrict__ LS,
    float* __restrict__ ws_val, int* __restrict__ ws_idx, int k)
{
    __shared__ float sv[4]; __shared__ int si[4];
    const int tid  = threadIdx.x;
    const int b    = blockIdx.x >> 4;
    const int pix  = (blockIdx.x & 15) * 1024 + tid * 4;
    const int gpix = b * NPIX + pix;
    const float sigma = expf(log_sigma[0]);

    float seed[CDIM];
#pragma unroll
    for (int o = 0; o < CDIM; o++) seed[o] = seed_ws[b * CDIM + o];

    float4 ls;
    if (k == 0) ls = make_float4(0.f, 0.f, 0.f, 0.f);
    else        ls = *(const float4*)(LS + k * SLAB + gpix);

    float d2x = 0.f, d2y = 0.f, d2z = 0.f, d2w = 0.f;
#pragma unroll
    for (int o = 0; o < CDIM; o++) {
        const float4 c = *(const float4*)(colour + (b * CDIM + o) * NPIX + pix);
        const float s  = seed[o];
        const float tx = c.x - s, ty = c.y - s, tz = c.z - s, tw = c.w - s;
        d2x += tx * tx; d2y += ty * ty; d2z += tz * tz; d2w += tw * tw;
    }

    float ax = expf(-d2x / sigma), ay = expf(-d2y / sigma);
    float az = expf(-d2z / sigma), aw = expf(-d2w / sigma);
    // clamp_st forward pass == clip
    ax = fminf(fmaxf(ax, 0.01f), 0.99f); ay = fminf(fmaxf(ay, 0.01f), 0.99f);
    az = fminf(fmaxf(az, 0.01f), 0.99f); aw = fminf(fmaxf(aw, 0.01f), 0.99f);

    const float4 lm  = { ls.x + logf(ax),     ls.y + logf(ay),
                         ls.z + logf(az),     ls.w + logf(aw) };
    const float4 nls = { ls.x + log1pf(-ax),  ls.y + log1pf(-ay),
                         ls.z + log1pf(-az),  ls.w + log1pf(-aw) };

    if (k == 0) *(float4*)(LS + gpix) = make_float4(0.f, 0.f, 0.f, 0.f); // log_s_k[0]
    *(float4*)(LM + k * SLAB + gpix) = lm;               // log_m_k[k]
    *(float4*)(LS + (k + 1) * SLAB + gpix) = nls;        // log_s_k[k+1]

    if (k == KSTEPS - 1) {
        *(float4*)(LM + KSTEPS * SLAB + gpix) = nls;     // log_m_k[K] = final log_s
    } else {
        // argmax partials for step k+1: pp = rand * exp(new_log_s)
        const float4 r = *(const float4*)(randp + gpix);
        const float px = r.x * expf(nls.x), py = r.y * expf(nls.y);
        const float pz = r.z * expf(nls.z), pw = r.w * expf(nls.w);
        float v = px; int idx = pix;
        amax_comb(v, idx, py, pix + 1);
        amax_comb(v, idx, pz, pix + 2);
        amax_comb(v, idx, pw, pix + 3);
        wave_argmax(v, idx);
        if ((tid & 63) == 0) { sv[tid >> 6] = v; si[tid >> 6] = idx; }
        __syncthreads();
        if (tid == 0) {
#pragma unroll
            for (int w = 1; w < 4; w++) amax_comb(v, idx, sv[w], si[w]);
            ws_val[blockIdx.x] = v; ws_idx[blockIdx.x] = idx;
        }
    }
}

extern "C" void kernel_launch(void* const* d_in, const int* in_sizes, int n_in,
                              void* d_out, int out_size, void* d_ws, size_t ws_size,
                              hipStream_t stream) {
    const float* feat      = (const float*)d_in[0];
    const float* randp     = (const float*)d_in[1];
    const float* conv_w    = (const float*)d_in[2];
    const float* conv_b    = (const float*)d_in[3];
    const float* gate      = (const float*)d_in[4];
    const float* log_sigma = (const float*)d_in[5];
    const float* uv        = (const float*)d_in[6];

    float* out    = (float*)d_out;
    // concat(log_m_k[8,32,1,128,128], log_s_k[8,...], seeds[7,32,8], colour[32,8,128,128], delta[32,2,128,128])
    float* LM     = out;                         // 4,194,304
    float* LS     = out + 4194304;               // 4,194,304
    float* SEEDS  = out + 8388608;               // 1,792
    float* COLOUR = out + 8390400;               // 4,194,304
    float* DELTA  = out + 12584704;              // 1,048,576

    float* ws_val  = (float*)d_ws;                       // 512 floats
    int*   ws_idx  = (int*)((char*)d_ws + 2048);         // 512 ints
    float* seed_ws = (float*)((char*)d_ws + 4096);       // 256 floats

    conv_kernel<<<512, 256, 0, stream>>>(feat, randp, conv_w, conv_b, gate, uv,
                                         COLOUR, DELTA, ws_val, ws_idx);
    for (int k = 0; k < KSTEPS; k++) {
        reduce_seed_kernel<<<32, 64, 0, stream>>>(ws_val, ws_idx, COLOUR,
                                                  seed_ws, SEEDS, k);
        step_kernel<<<512, 256, 0, stream>>>(COLOUR, randp, log_sigma, seed_ws,
                                             LM, LS, ws_val, ws_idx, k);
    }
}